// Round 6
// baseline (276.094 us; speedup 1.0000x reference)
//
#include <hip/hip_runtime.h>

// sparsemax over axis=2 of x[8][16][4096][64] (fp32).
// 8192 vectors of length 4096, stride 64 floats.
//
// R1 evidence: dur 113us, FETCH/WRITE exactly 131MB each, HBM 30%, VGPR=44.
// VGPR=44 proves the compiler rematerialized c[16] (needs 64 VGPRs) -> 3 read
// passes (L3-absorbed, so FETCH stayed clean) + phase-locked load/store bubbles.
//
// Fix: PIN each of the 16 float4 loads with an empty asm ("+v") so the values
// are asm-defined -> rematerialization impossible; data stays in VGPRs across
// extract + store passes. ~110 VGPR, 1 block/CU by design (bandwidth kernel,
// 256KB in flight per CU).
//
// Numerics: Newton in the reference's SHIFTED domain z = x - max (same
// rounding as reference), candidates z > -1 (tau_z >= -1 always), output
// relu(z - tau_z). Newton-from-below on the piecewise-linear
// f(tau) = sum relu(z - tau) - 1 is exact (monotone ascent, finite breakpoints,
// bitwise fixed-point termination) -> matches the sort-based reference.
//
// Layout: 1 block (1024 thr) per (bh slab, 16-wide d-tile): 512 blocks.
// Thread t: dq = t&3 (float4 col), iblk = t>>2; rows i = iblk + 256*s.
// Lanes 0..3 cover one full 64B line -> perfectly coalesced load/store.

#define C_CAP 256

typedef float f32x4 __attribute__((ext_vector_type(4)));

__global__ __launch_bounds__(1024, 4)
void sparsemax_ax2_kernel(const float* __restrict__ x, float* __restrict__ out)
{
    const int b   = blockIdx.x;
    const int bh  = b >> 2;             // (batch*heads) slab 0..127
    const int dt  = b & 3;              // which 16-wide d tile

    const int t    = threadIdx.x;       // 0..1023
    const int lane = t & 63;
    const int wv   = t >> 6;            // 0..15
    const int dq   = t & 3;             // float4 column within d-tile
    const int iblk = t >> 2;            // 0..255

    __shared__ float list[16][C_CAP];   // candidate z-values per vector
    __shared__ float redbuf[256];       // 16 waves x 16 vectors partial maxes
    __shared__ float gmaxT[16];
    __shared__ float tauLDS[16];
    __shared__ int   cnt[16];

    const f32x4* __restrict__ x4 = reinterpret_cast<const f32x4*>(x);
    f32x4* __restrict__ o4       = reinterpret_cast<f32x4*>(out);

    const size_t slabrow = (size_t)bh * 4096;
    // float4-index of (row iblk, col 16*dt + 4*dq); row stride = 16 float4
    const size_t idx0 = (slabrow + (size_t)iblk) * 16 + (size_t)(dt * 4) + (size_t)dq;

    // ---- load: 16 float4 per thread ----
    f32x4 c[16];
#pragma unroll
    for (int s = 0; s < 16; ++s)
        c[s] = x4[idx0 + (size_t)s * 4096];   // i += 256 per step

    // ---- per-vector max (consumes the fresh loads) ----
    f32x4 m = c[0];
#pragma unroll
    for (int s = 1; s < 16; ++s) {
        m.x = fmaxf(m.x, c[s].x);
        m.y = fmaxf(m.y, c[s].y);
        m.z = fmaxf(m.z, c[s].z);
        m.w = fmaxf(m.w, c[s].w);
    }

    // ---- pin: each value becomes asm-defined -> no rematerialization ----
#pragma unroll
    for (int s = 0; s < 16; ++s)
        asm volatile("" : "+v"(c[s]));

    // segmented butterfly: xor masks 4..32 stay within same-dq lane class
#pragma unroll
    for (int mask = 4; mask <= 32; mask <<= 1) {
        m.x = fmaxf(m.x, __shfl_xor(m.x, mask));
        m.y = fmaxf(m.y, __shfl_xor(m.y, mask));
        m.z = fmaxf(m.z, __shfl_xor(m.z, mask));
        m.w = fmaxf(m.w, __shfl_xor(m.w, mask));
    }
    if (lane < 4) {                     // lane == its dq class here
        redbuf[wv * 16 + lane * 4 + 0] = m.x;
        redbuf[wv * 16 + lane * 4 + 1] = m.y;
        redbuf[wv * 16 + lane * 4 + 2] = m.z;
        redbuf[wv * 16 + lane * 4 + 3] = m.w;
    }
    __syncthreads();
    if (t < 16) {
        float g = redbuf[t];
#pragma unroll
        for (int w = 1; w < 16; ++w) g = fmaxf(g, redbuf[w * 16 + t]);
        gmaxT[t] = g;
        cnt[t]   = 0;
    }
    __syncthreads();

    // ---- candidate extraction in the shifted domain: z = x - gmax, keep z > -1
    //      (tau_z >= -1, so nothing else can be in the support) ----
    const int j0 = dq << 2;
    f32x4 g4;
    g4.x = gmaxT[j0 + 0];
    g4.y = gmaxT[j0 + 1];
    g4.z = gmaxT[j0 + 2];
    g4.w = gmaxT[j0 + 3];

#pragma unroll
    for (int s = 0; s < 16; ++s) {
        float zx = c[s].x - g4.x;
        float zy = c[s].y - g4.y;
        float zz = c[s].z - g4.z;
        float zw = c[s].w - g4.w;
        if (zx > -1.0f) { int p = atomicAdd(&cnt[j0+0], 1); if (p < C_CAP) list[j0+0][p] = zx; }
        if (zy > -1.0f) { int p = atomicAdd(&cnt[j0+1], 1); if (p < C_CAP) list[j0+1][p] = zy; }
        if (zz > -1.0f) { int p = atomicAdd(&cnt[j0+2], 1); if (p < C_CAP) list[j0+2][p] = zz; }
        if (zw > -1.0f) { int p = atomicAdd(&cnt[j0+3], 1); if (p < C_CAP) list[j0+3][p] = zw; }
    }
    __syncthreads();

    // ---- Newton from below (one wave per vector), exact for piecewise-linear f ----
    {
        const int j = wv;
        const int n = cnt[j];
        float tau = -1.0f;
        if (n <= C_CAP) {
            for (int it = 0; it < 100; ++it) {
                float sv = 0.f, cc = 0.f;
                for (int p = lane; p < n; p += 64) {
                    float v = list[j][p];
                    if (v > tau) { sv += v; cc += 1.f; }
                }
#pragma unroll
                for (int mask = 1; mask <= 32; mask <<= 1) {
                    sv += __shfl_xor(sv, mask);
                    cc += __shfl_xor(cc, mask);
                }
                if (cc < 0.5f) break;                 // can't happen; safety
                float tn = (sv - 1.0f) / cc;
                tn = fmaxf(tn, tau);                  // enforce monotone ascent
                if (tn == tau) break;                 // fixed point reached
                tau = tn;
            }
        } else {
            // overflow fallback: re-read whole vector from global (L3-warm). Rare.
            const float g = gmaxT[j];
            const float* vb = x + slabrow * 64 + (size_t)(dt * 16 + j);
            for (int it = 0; it < 100; ++it) {
                float sv = 0.f, cc = 0.f;
                for (int p = lane; p < 4096; p += 64) {
                    float v = vb[(size_t)p * 64] - g;
                    if (v > tau) { sv += v; cc += 1.f; }
                }
#pragma unroll
                for (int mask = 1; mask <= 32; mask <<= 1) {
                    sv += __shfl_xor(sv, mask);
                    cc += __shfl_xor(cc, mask);
                }
                if (cc < 0.5f) break;
                float tn = (sv - 1.0f) / cc;
                tn = fmaxf(tn, tau);
                if (tn == tau) break;
                tau = tn;
            }
        }
        if (lane == 0) tauLDS[j] = tau;
    }
    __syncthreads();

    // ---- output: relu((x - gmax) - tau), same rounding as reference ----
    f32x4 tau4;
    tau4.x = tauLDS[j0 + 0];
    tau4.y = tauLDS[j0 + 1];
    tau4.z = tauLDS[j0 + 2];
    tau4.w = tauLDS[j0 + 3];
#pragma unroll
    for (int s = 0; s < 16; ++s) {
        f32x4 o;
        o.x = fmaxf((c[s].x - g4.x) - tau4.x, 0.f);
        o.y = fmaxf((c[s].y - g4.y) - tau4.y, 0.f);
        o.z = fmaxf((c[s].z - g4.z) - tau4.z, 0.f);
        o.w = fmaxf((c[s].w - g4.w) - tau4.w, 0.f);
        o4[idx0 + (size_t)s * 4096] = o;
    }
}

extern "C" void kernel_launch(void* const* d_in, const int* in_sizes, int n_in,
                              void* d_out, int out_size, void* d_ws, size_t ws_size,
                              hipStream_t stream)
{
    (void)n_in; (void)d_ws; (void)ws_size; (void)out_size;
    const float* x = (const float*)d_in[0];
    float* out     = (float*)d_out;
    const int total = in_sizes[0];            // 8*16*4096*64
    const int slabs = total / (4096 * 64);    // 128
    dim3 grid(slabs * 4), block(1024);
    hipLaunchKernelGGL(sparsemax_ax2_kernel, grid, block, 0, stream, x, out);
}

// Round 7
// 270.928 us; speedup vs baseline: 1.0191x; 1.0191x over previous
//
#include <hip/hip_runtime.h>

// sparsemax over axis=2 of x[8][16][4096][64] (fp32), two-pass split.
//
// R6 post-mortem: pinning changed nothing (dur 113us, VGPR=44 in both R1/R6).
// The single phase-locked 1024-thr kernel is capped at ~2.35 TB/s effective
// (262MB/113us) with all pipes idle -> structural, not remat. Split the op:
//
//   Pass 1 (tau):  proven coalesced tile read -> max -> candidates -> Newton;
//                  writes only gmax[8192], tau[8192] to d_ws (64 KB).
//                  131 MB read, ~0 write.
//   Pass 2 (apply): textbook grid-stride float4 stream:
//                  out = relu((x - gmax) - tau). 131 MB read + 131 MB write.
//
// Each dispatch profiles separately -> independent BW measurement of the
// tiled-read pattern (P1) and a pure stream (P2) in one bench round.
//
// Numerics identical to R6 (absmax 0.0): shifted domain z = x - gmax,
// Newton-from-below on piecewise-linear f(tau)=sum relu(z-tau)-1 (exact),
// output relu((x - gmax) - tau) with the same two-step rounding.

#define C_CAP 256

typedef float f32x4 __attribute__((ext_vector_type(4)));

// ---------------------------------------------------------------- pass 1 ----
__global__ __launch_bounds__(1024, 4)
void sparsemax_tau_kernel(const float* __restrict__ x,
                          float* __restrict__ gmax_out,   // [128*64]
                          float* __restrict__ tau_out)    // [128*64]
{
    const int b   = blockIdx.x;
    const int bh  = b >> 2;             // slab 0..127
    const int dt  = b & 3;              // 16-wide d tile

    const int t    = threadIdx.x;       // 0..1023
    const int lane = t & 63;
    const int wv   = t >> 6;            // 0..15
    const int dq   = t & 3;             // float4 column within d-tile
    const int iblk = t >> 2;            // 0..255

    __shared__ float list[16][C_CAP];
    __shared__ float redbuf[256];
    __shared__ float gmaxT[16];
    __shared__ int   cnt[16];

    const f32x4* __restrict__ x4 = reinterpret_cast<const f32x4*>(x);

    const size_t slabrow = (size_t)bh * 4096;
    const size_t idx0 = (slabrow + (size_t)iblk) * 16 + (size_t)(dt * 4) + (size_t)dq;

    // ---- load 16 float4/thread (rows iblk + 256*s), coalesced 1KB chunks ----
    f32x4 c[16];
#pragma unroll
    for (int s = 0; s < 16; ++s)
        c[s] = x4[idx0 + (size_t)s * 4096];

    // ---- per-vector max ----
    f32x4 m = c[0];
#pragma unroll
    for (int s = 1; s < 16; ++s) {
        m.x = fmaxf(m.x, c[s].x);
        m.y = fmaxf(m.y, c[s].y);
        m.z = fmaxf(m.z, c[s].z);
        m.w = fmaxf(m.w, c[s].w);
    }
#pragma unroll
    for (int mask = 4; mask <= 32; mask <<= 1) {
        m.x = fmaxf(m.x, __shfl_xor(m.x, mask));
        m.y = fmaxf(m.y, __shfl_xor(m.y, mask));
        m.z = fmaxf(m.z, __shfl_xor(m.z, mask));
        m.w = fmaxf(m.w, __shfl_xor(m.w, mask));
    }
    if (lane < 4) {
        redbuf[wv * 16 + lane * 4 + 0] = m.x;
        redbuf[wv * 16 + lane * 4 + 1] = m.y;
        redbuf[wv * 16 + lane * 4 + 2] = m.z;
        redbuf[wv * 16 + lane * 4 + 3] = m.w;
    }
    __syncthreads();
    if (t < 16) {
        float g = redbuf[t];
#pragma unroll
        for (int w = 1; w < 16; ++w) g = fmaxf(g, redbuf[w * 16 + t]);
        gmaxT[t] = g;
        cnt[t]   = 0;
    }
    __syncthreads();

    // ---- candidate extraction: z = x - gmax, keep z > -1 ----
    const int j0 = dq << 2;
    f32x4 g4;
    g4.x = gmaxT[j0 + 0];
    g4.y = gmaxT[j0 + 1];
    g4.z = gmaxT[j0 + 2];
    g4.w = gmaxT[j0 + 3];

#pragma unroll
    for (int s = 0; s < 16; ++s) {
        float zx = c[s].x - g4.x;
        float zy = c[s].y - g4.y;
        float zz = c[s].z - g4.z;
        float zw = c[s].w - g4.w;
        if (zx > -1.0f) { int p = atomicAdd(&cnt[j0+0], 1); if (p < C_CAP) list[j0+0][p] = zx; }
        if (zy > -1.0f) { int p = atomicAdd(&cnt[j0+1], 1); if (p < C_CAP) list[j0+1][p] = zy; }
        if (zz > -1.0f) { int p = atomicAdd(&cnt[j0+2], 1); if (p < C_CAP) list[j0+2][p] = zz; }
        if (zw > -1.0f) { int p = atomicAdd(&cnt[j0+3], 1); if (p < C_CAP) list[j0+3][p] = zw; }
    }
    __syncthreads();

    // ---- Newton from below (one wave per vector), exact ----
    {
        const int j = wv;
        const int n = cnt[j];
        float tau = -1.0f;
        if (n <= C_CAP) {
            for (int it = 0; it < 100; ++it) {
                float sv = 0.f, cc = 0.f;
                for (int p = lane; p < n; p += 64) {
                    float v = list[j][p];
                    if (v > tau) { sv += v; cc += 1.f; }
                }
#pragma unroll
                for (int mask = 1; mask <= 32; mask <<= 1) {
                    sv += __shfl_xor(sv, mask);
                    cc += __shfl_xor(cc, mask);
                }
                if (cc < 0.5f) break;
                float tn = (sv - 1.0f) / cc;
                tn = fmaxf(tn, tau);
                if (tn == tau) break;
                tau = tn;
            }
        } else {
            // overflow fallback (never taken for Gaussian data): global re-read
            const float g = gmaxT[j];
            const float* vb = x + slabrow * 64 + (size_t)(dt * 16 + j);
            for (int it = 0; it < 100; ++it) {
                float sv = 0.f, cc = 0.f;
                for (int p = lane; p < 4096; p += 64) {
                    float v = vb[(size_t)p * 64] - g;
                    if (v > tau) { sv += v; cc += 1.f; }
                }
#pragma unroll
                for (int mask = 1; mask <= 32; mask <<= 1) {
                    sv += __shfl_xor(sv, mask);
                    cc += __shfl_xor(cc, mask);
                }
                if (cc < 0.5f) break;
                float tn = (sv - 1.0f) / cc;
                tn = fmaxf(tn, tau);
                if (tn == tau) break;
                tau = tn;
            }
        }
        if (lane == 0) {
            const int vec = bh * 64 + dt * 16 + j;   // [bh][d] layout
            gmax_out[vec] = gmaxT[j];
            tau_out[vec]  = tau;
        }
    }
}

// ---------------------------------------------------------------- pass 2 ----
__global__ __launch_bounds__(256)
void sparsemax_apply_kernel(const float* __restrict__ x,
                            const float* __restrict__ gmax_in,
                            const float* __restrict__ tau_in,
                            float* __restrict__ out, int n4)
{
    const f32x4* __restrict__ x4 = reinterpret_cast<const f32x4*>(x);
    const f32x4* __restrict__ g4 = reinterpret_cast<const f32x4*>(gmax_in);
    const f32x4* __restrict__ t4 = reinterpret_cast<const f32x4*>(tau_in);
    f32x4* __restrict__ o4       = reinterpret_cast<f32x4*>(out);

    const int stride = gridDim.x * 256;
    for (int f = blockIdx.x * 256 + threadIdx.x; f < n4; f += stride) {
        const int d4 = f & 15;          // which float4 of the 64-wide d dim
        const int bh = f >> 16;         // 4096*16 float4 per slab
        const int v  = bh * 16 + d4;    // float4 index into [bh][64] tables
        f32x4 xv = x4[f];
        f32x4 g  = g4[v];
        f32x4 tv = t4[v];
        f32x4 o;
        o.x = fmaxf((xv.x - g.x) - tv.x, 0.f);
        o.y = fmaxf((xv.y - g.y) - tv.y, 0.f);
        o.z = fmaxf((xv.z - g.z) - tv.z, 0.f);
        o.w = fmaxf((xv.w - g.w) - tv.w, 0.f);
        o4[f] = o;
    }
}

extern "C" void kernel_launch(void* const* d_in, const int* in_sizes, int n_in,
                              void* d_out, int out_size, void* d_ws, size_t ws_size,
                              hipStream_t stream)
{
    (void)n_in; (void)ws_size; (void)out_size;
    const float* x = (const float*)d_in[0];
    float* out     = (float*)d_out;
    const int total = in_sizes[0];            // 8*16*4096*64 = 33554432
    const int slabs = total / (4096 * 64);    // 128
    const int n4    = total / 4;              // float4 count

    float* gmax = (float*)d_ws;               // 8192 floats
    float* tau  = gmax + slabs * 64;          // 8192 floats (64 KB total in d_ws)

    hipLaunchKernelGGL(sparsemax_tau_kernel, dim3(slabs * 4), dim3(1024), 0, stream,
                       x, gmax, tau);
    hipLaunchKernelGGL(sparsemax_apply_kernel, dim3(2048), dim3(256), 0, stream,
                       x, gmax, tau, out, n4);
}